// Round 5
// baseline (25.294 us; speedup 1.0000x reference)
//
#include <hip/hip_runtime.h>

// Problem constants (match reference setup_inputs)
#define BB 4
#define HH 1024
#define WW 1024
#define NC 12
#define GD 16
#define GH 16
#define GW 8

// LDS slab H[row][x][z][c]: one dword = half2( F(x,z,c), F(x,z+1,c) )
// (z-duplicated f16, y already lerped). z-stride 12 dwords, x-stride 196.
// ds_read_b128 bank-quad group = (49x + 3z + q) mod 8 -> random z spreads
// near-uniformly over the 8 quad groups (~2-way, ~free).
#define ZSD 12
#define XSD 196
#define HSZ (GW * XSD)   // 1568 dwords = 6272 B per row slab

typedef _Float16 h2 __attribute__((ext_vector_type(2)));
union HU { uint u; h2 h; };

// x-lerp both z corners in packed f16, then z-lerp in f32.
#define CH(ua_, ub_, dst_) do {                                   \
    HU A_, B_; A_.u = (ua_); B_.u = (ub_);                        \
    h2 m_ = A_.h + wx2 * (B_.h - A_.h);                           \
    float m0_ = (float)m_.x;                                      \
    float m1_ = (float)m_.y;                                      \
    dst_ = fmaf(wz, m1_ - m0_, m0_);                              \
} while (0)

__device__ __forceinline__ void run4(const uint* __restrict__ Hs,
                                     const float4& r4, const float4& g4, const float4& b4,
                                     float* __restrict__ outp, int tid,
                                     size_t plane)
{
    const float* rp = (const float*)&r4;
    const float* gp = (const float*)&g4;
    const float* bp = (const float*)&b4;
    float4 o0, o1, o2;
    float* o0p = (float*)&o0; float* o1p = (float*)&o1; float* o2p = (float*)&o2;

#pragma unroll
    for (int p = 0; p < 4; p++) {
        const int px = 4 * tid + p;
        const float r = rp[p], g = gp[p], bl = bp[p];

        float ux = fminf(px * (7.0f / 1023.0f), 7.0f);
        int x0 = (int)ux;
        int x1 = min(x0 + 1, GW - 1);
        float wx = ux - (float)x0;
        _Float16 wxh = (_Float16)wx;
        h2 wx2 = h2{wxh, wxh};

        float lum = 0.299f * r + 0.587f * g + 0.114f * bl;
        float uz = fminf(fmaxf(lum * 15.0f, 0.0f), 15.0f);
        int z0 = (int)uz;
        float wz = uz - (float)z0;

        const uint* pa = Hs + x0 * XSD + z0 * ZSD;
        const uint* pb = Hs + x1 * XSD + z0 * ZSD;
        const uint4 qa0 = ((const uint4*)pa)[0];
        const uint4 qa1 = ((const uint4*)pa)[1];
        const uint4 qa2 = ((const uint4*)pa)[2];
        const uint4 qb0 = ((const uint4*)pb)[0];
        const uint4 qb1 = ((const uint4*)pb)[1];
        const uint4 qb2 = ((const uint4*)pb)[2];

        float c0, c1, c2, c3, c4, c5, c6, c7, c8, c9, c10, c11;
        CH(qa0.x, qb0.x, c0);  CH(qa0.y, qb0.y, c1);
        CH(qa0.z, qb0.z, c2);  CH(qa0.w, qb0.w, c3);
        CH(qa1.x, qb1.x, c4);  CH(qa1.y, qb1.y, c5);
        CH(qa1.z, qb1.z, c6);  CH(qa1.w, qb1.w, c7);
        CH(qa2.x, qb2.x, c8);  CH(qa2.y, qb2.y, c9);
        CH(qa2.z, qb2.z, c10); CH(qa2.w, qb2.w, c11);

        float v0 = c0 * r + c1 * g + c2  * bl + c9;
        float v1 = c3 * r + c4 * g + c5  * bl + c10;
        float v2 = c6 * r + c7 * g + c8  * bl + c11;
        o0p[p] = fminf(fmaxf(v0, 0.0f), 1.0f);
        o1p[p] = fminf(fmaxf(v1, 0.0f), 1.0f);
        o2p[p] = fminf(fmaxf(v2, 0.0f), 1.0f);
    }

    *(float4*)(outp + 4 * tid) = o0;
    *(float4*)(outp + 4 * tid + plane) = o1;
    *(float4*)(outp + 4 * tid + 2 * plane) = o2;
}

__global__ __launch_bounds__(256) void bgrid_row2(const float* __restrict__ img,
                                                  const float* __restrict__ grid,
                                                  float* __restrict__ out)
{
    const int yb = blockIdx.x * 2;          // rows yb, yb+1
    const int b = blockIdx.y;
    const int tid = threadIdx.x;

    __shared__ __align__(16) uint H[2][HSZ];   // 12.5 KB

    // ---- PREFETCH image for both rows FIRST (hide HBM latency under staging)
    const size_t plane = (size_t)HH * WW;
    const size_t rbase = (size_t)b * 3 * plane + (size_t)yb * WW;
    const float* ip = img + rbase + 4 * tid;
    const float4 rA = *(const float4*)(ip);
    const float4 gA = *(const float4*)(ip + plane);
    const float4 bA = *(const float4*)(ip + 2 * plane);
    const float4 rB = *(const float4*)(ip + WW);
    const float4 gB = *(const float4*)(ip + WW + plane);
    const float4 bB = *(const float4*)(ip + WW + 2 * plane);

    // ---- per-row y interpolation constants (block-uniform) ----
    float uyA = fminf(yb * (15.0f / 1023.0f), 15.0f);
    int yA0 = (int)uyA;
    int yA1 = min(yA0 + 1, GH - 1);
    float wyA = uyA - (float)yA0;
    float uyB = fminf((yb + 1) * (15.0f / 1023.0f), 15.0f);
    int yB0 = (int)uyB;
    int yB1 = min(yB0 + 1, GH - 1);
    float wyB = uyB - (float)yB0;

    // ---- stage y-lerped, z-dup'd f16 slabs for both rows ----
    const float* gbase = grid + (size_t)b * (NC * GD * GH * GW); // [c][z][y][x]
#pragma unroll
    for (int j = 0; j < 6; j++) {
        int t = tid + 256 * j;          // 0..1535 = 8x * 16z * 12c
        int x = t & 7;
        int z = (t >> 3) & 15;
        int c = t >> 7;
        int zp = min(z + 1, GD - 1);
        const float* bc = gbase + c * (GD * GH * GW) + x;
        float a0 = bc[(z  * GH + yA0) * GW];
        float a1 = bc[(z  * GH + yA1) * GW];
        float e0 = bc[(zp * GH + yA0) * GW];
        float e1 = bc[(zp * GH + yA1) * GW];
        float d0 = bc[(z  * GH + yB0) * GW];
        float d1 = bc[(z  * GH + yB1) * GW];
        float f0 = bc[(zp * GH + yB0) * GW];
        float f1 = bc[(zp * GH + yB1) * GW];
        HU pa, pb;
        pa.h = h2{(_Float16)fmaf(wyA, a1 - a0, a0),
                  (_Float16)fmaf(wyA, e1 - e0, e0)};
        pb.h = h2{(_Float16)fmaf(wyB, d1 - d0, d0),
                  (_Float16)fmaf(wyB, f1 - f0, f0)};
        int off = x * XSD + z * ZSD + c;
        H[0][off] = pa.u;
        H[1][off] = pb.u;
    }
    __syncthreads();

    // ---- row A then row B (independent chains; image already in regs) ----
    run4(H[0], rA, gA, bA, out + rbase, tid, plane);
    run4(H[1], rB, gB, bB, out + rbase + WW, tid, plane);
}

extern "C" void kernel_launch(void* const* d_in, const int* in_sizes, int n_in,
                              void* d_out, int out_size, void* d_ws, size_t ws_size,
                              hipStream_t stream) {
    const float* grid  = (const float*)d_in[0];
    const float* image = (const float*)d_in[1];
    float* out = (float*)d_out;

    dim3 blk(256);
    dim3 grd(HH / 2, BB);   // one block per (2 rows, batch)
    bgrid_row2<<<grd, blk, 0, stream>>>(image, grid, out);
}